// Round 1
// baseline (297.136 us; speedup 1.0000x reference)
//
#include <hip/hip_runtime.h>

#define N_FEAT 784
#define NF4    196          // N_FEAT / 4
#define N_CLS  10

// Folded network: logits = x @ Weff^T + beff; out = softmax(logits).
// Weff/beff recomputed per block into LDS (inputs L2/L3-hot).
// Main loop: 16-lane group owns 4 rows (single pass, 16 rows/wave);
// x read directly from global (coalesced 256B segments); Weff via
// conflict-free broadcast ds_read_b128 amortized across 4 rows.
__global__ __launch_bounds__(256, 4) void sparse_fused_kernel(
    const float* __restrict__ x,
    const float* __restrict__ Wsp,   // [784,2]
    const float* __restrict__ bsp,   // [784,2]
    const float* __restrict__ fcw,   // [10,784]
    const float* __restrict__ fcb,   // [10]
    float* __restrict__ out)         // [65536,10]
{
    __shared__ float Wl[N_CLS * N_FEAT];   // folded weights, [10][784]
    __shared__ float bl[N_CLS];            // folded bias
    __shared__ float bred[4][N_CLS];

    const int tid  = threadIdx.x;
    const int lane = tid & 63;
    const int wave = tid >> 6;

    // ---- per-block fold of the sparse layer into fc ----
    float bacc[N_CLS];
#pragma unroll
    for (int n = 0; n < N_CLS; ++n) bacc[n] = 0.f;

    for (int i = tid; i < N_FEAT; i += 256) {
        // scatter map from the reference (incl. the i==782 wraparound bug)
        int c0 = (i == 782) ? 0 : i;
        int c1 = (i == 782) ? 1 : ((i == 783) ? 0 : (i + 1));
        float w0 = Wsp[2 * i], w1 = Wsp[2 * i + 1];
        float b0 = bsp[2 * i], b1 = bsp[2 * i + 1];
#pragma unroll
        for (int n = 0; n < N_CLS; ++n) {
            float f0 = fcw[n * N_FEAT + c0];
            float f1 = fcw[n * N_FEAT + c1];
            Wl[n * N_FEAT + i] = f0 * w0 + f1 * w1;
            bacc[n] += f0 * b0 + f1 * b1;
        }
    }
#pragma unroll
    for (int n = 0; n < N_CLS; ++n) {
#pragma unroll
        for (int d = 1; d < 64; d <<= 1)
            bacc[n] += __shfl_xor(bacc[n], d, 64);
    }
    if (lane == 0) {
#pragma unroll
        for (int n = 0; n < N_CLS; ++n) bred[wave][n] = bacc[n];
    }
    __syncthreads();
    if (tid < N_CLS)
        bl[tid] = bred[0][tid] + bred[1][tid] + bred[2][tid] + bred[3][tid] + fcb[tid];
    __syncthreads();

    // ---- main GEMM + softmax ----
    const float4* Wl4 = (const float4*)Wl;
    const int gw = blockIdx.x * 4 + wave;   // global wave id, 0..4095
    const int g  = lane >> 4;               // 16-lane group, 0..3
    const int sl = lane & 15;

    // single pass: wave covers 16 rows, group g owns rows rbase..rbase+3
    const int rbase = gw * 16 + g * 4;
    const float4* xr = (const float4*)(x + (size_t)rbase * N_FEAT);

    float acc[4][N_CLS];
#pragma unroll
    for (int r = 0; r < 4; ++r)
#pragma unroll
        for (int n = 0; n < N_CLS; ++n) acc[r][n] = 0.f;

    // lanes stride the 196 float4 features; 12 full steps (fixed trip) + tail
#pragma unroll 2
    for (int i = 0; i < 12; ++i) {
        const int k4 = sl + 16 * i;
        float4 x0 = xr[k4];
        float4 x1 = xr[NF4 + k4];
        float4 x2 = xr[2 * NF4 + k4];
        float4 x3 = xr[3 * NF4 + k4];
#pragma unroll
        for (int n = 0; n < N_CLS; ++n) {
            float4 wv = Wl4[n * NF4 + k4];
            acc[0][n] += wv.x * x0.x + wv.y * x0.y + wv.z * x0.z + wv.w * x0.w;
            acc[1][n] += wv.x * x1.x + wv.y * x1.y + wv.z * x1.z + wv.w * x1.w;
            acc[2][n] += wv.x * x2.x + wv.y * x2.y + wv.z * x2.z + wv.w * x2.w;
            acc[3][n] += wv.x * x3.x + wv.y * x3.y + wv.z * x3.z + wv.w * x3.w;
        }
    }
    if (sl < 4) {                       // k4 = 192..195
        const int k4 = 192 + sl;
        float4 x0 = xr[k4];
        float4 x1 = xr[NF4 + k4];
        float4 x2 = xr[2 * NF4 + k4];
        float4 x3 = xr[3 * NF4 + k4];
#pragma unroll
        for (int n = 0; n < N_CLS; ++n) {
            float4 wv = Wl4[n * NF4 + k4];
            acc[0][n] += wv.x * x0.x + wv.y * x0.y + wv.z * x0.z + wv.w * x0.w;
            acc[1][n] += wv.x * x1.x + wv.y * x1.y + wv.z * x1.z + wv.w * x1.w;
            acc[2][n] += wv.x * x2.x + wv.y * x2.y + wv.z * x2.z + wv.w * x2.w;
            acc[3][n] += wv.x * x3.x + wv.y * x3.y + wv.z * x3.z + wv.w * x3.w;
        }
    }

    // intra-group (16-lane) butterfly; all 4 groups reduce in parallel
#pragma unroll
    for (int d = 1; d < 16; d <<= 1) {
#pragma unroll
        for (int r = 0; r < 4; ++r)
#pragma unroll
            for (int n = 0; n < N_CLS; ++n)
                acc[r][n] += __shfl_xor(acc[r][n], d, 64);
    }

    // fused softmax per row (computed redundantly in all 16 lanes)
#pragma unroll
    for (int r = 0; r < 4; ++r) {
        float m = -1e30f;
#pragma unroll
        for (int n = 0; n < N_CLS; ++n) {
            acc[r][n] += bl[n];
            m = fmaxf(m, acc[r][n]);
        }
        float den = 0.f;
#pragma unroll
        for (int n = 0; n < N_CLS; ++n) {
            acc[r][n] = __expf(acc[r][n] - m);
            den += acc[r][n];
        }
        float inv = 1.0f / den;
        float v = acc[r][0];
#pragma unroll
        for (int n = 1; n < N_CLS; ++n) v = (sl == n) ? acc[r][n] : v;
        if (sl < N_CLS)
            out[(size_t)(rbase + r) * N_CLS + sl] = v * inv;
    }
}

extern "C" void kernel_launch(void* const* d_in, const int* in_sizes, int n_in,
                              void* d_out, int out_size, void* d_ws, size_t ws_size,
                              hipStream_t stream) {
    const float* x   = (const float*)d_in[0];   // [65536,784]
    const float* Wsp = (const float*)d_in[1];   // [784,2]
    const float* bsp = (const float*)d_in[2];   // [784,2]
    const float* fcw = (const float*)d_in[3];   // [10,784]
    const float* fcb = (const float*)d_in[4];   // [10]
    float* out = (float*)d_out;                 // [65536,10]

    // 1024 blocks x 256 threads = exactly 4 blocks/CU co-resident;
    // 4 waves/block, 16 rows per wave (4 rows per 16-lane group), single pass
    sparse_fused_kernel<<<1024, 256, 0, stream>>>(x, Wsp, bsp, fcw, fcb, out);
}